// Round 1
// baseline (1027.356 us; speedup 1.0000x reference)
//
#include <hip/hip_runtime.h>
#include <hip/hip_bf16.h>

#define N_NODES 100000
#define N_EDGES 3200000
#define T_BUCKETS 8
#define F_DIM 64
#define N_SEGS (N_NODES * T_BUCKETS)   // 800000

typedef __attribute__((ext_vector_type(8))) short short8;
typedef __attribute__((ext_vector_type(4))) float floatx4;

__device__ __forceinline__ float bf2f(unsigned short u) {
    unsigned int x = ((unsigned int)u) << 16;
    return __builtin_bit_cast(float, x);
}
__device__ __forceinline__ unsigned short f2bf(float f) {
    unsigned int u = __builtin_bit_cast(unsigned int, f);
    unsigned int r = (u + 0x7FFFu + ((u >> 16) & 1u)) >> 16;
    return (unsigned short)r;
}

// ---------------- counting sort by segment (dst*8 + t) ----------------

__global__ void k_hist(const int* __restrict__ ei, const int* __restrict__ ti,
                       int* __restrict__ deg) {
    int e = blockIdx.x * 256 + threadIdx.x;
    if (e < N_EDGES) {
        int seg = (ei[N_EDGES + e] << 3) | ti[e];
        atomicAdd(&deg[seg], 1);
    }
}

__global__ void k_scan_a(const int* __restrict__ deg, int* __restrict__ part,
                         int* __restrict__ bsum) {
    __shared__ int s[1024];
    int i = blockIdx.x * 1024 + threadIdx.x;
    int v = (i < N_SEGS) ? deg[i] : 0;
    s[threadIdx.x] = v;
    __syncthreads();
    for (int off = 1; off < 1024; off <<= 1) {
        int t = (threadIdx.x >= off) ? s[threadIdx.x - off] : 0;
        __syncthreads();
        s[threadIdx.x] += t;
        __syncthreads();
    }
    if (i < N_SEGS) part[i] = s[threadIdx.x] - v;   // exclusive
    if (threadIdx.x == 1023) bsum[blockIdx.x] = s[1023];
}

__global__ void k_scan_b(const int* __restrict__ bsum, int* __restrict__ bscan, int nb) {
    __shared__ int s[1024];
    int v = ((int)threadIdx.x < nb) ? bsum[threadIdx.x] : 0;
    s[threadIdx.x] = v;
    __syncthreads();
    for (int off = 1; off < 1024; off <<= 1) {
        int t = (threadIdx.x >= off) ? s[threadIdx.x - off] : 0;
        __syncthreads();
        s[threadIdx.x] += t;
        __syncthreads();
    }
    if ((int)threadIdx.x < nb) bscan[threadIdx.x] = s[threadIdx.x] - v;
}

__global__ void k_scan_c(const int* __restrict__ part, const int* __restrict__ bscan,
                         int* __restrict__ seg_ptr, int* __restrict__ cursor) {
    int i = blockIdx.x * 1024 + threadIdx.x;
    if (i < N_SEGS) {
        int r = part[i] + bscan[i >> 10];
        seg_ptr[i] = r;
        cursor[i] = r;
    }
    if (i == 0) seg_ptr[N_SEGS] = N_EDGES;
}

__global__ void k_scatter(const int* __restrict__ ei, const int* __restrict__ ti,
                          int* __restrict__ cursor, int* __restrict__ gidx) {
    int e = blockIdx.x * 256 + threadIdx.x;
    if (e < N_EDGES) {
        int seg = (ei[N_EDGES + e] << 3) | ti[e];
        int pos = atomicAdd(&cursor[seg], 1);
        gidx[pos] = ei[e];                 // source node id, sorted by segment
    }
}

// ---------------- fp32 -> bf16 table conversion ----------------

__global__ void k_cvt(const float* __restrict__ x, unsigned short* __restrict__ xb) {
    int i = blockIdx.x * 256 + threadIdx.x;
    if (i < N_NODES * F_DIM) xb[i] = f2bf(x[i]);
}

// ---------------- pull aggregation: agg[n][t*64+f] = sum over edges ----------------

__device__ __forceinline__ void run_seg(const int* __restrict__ gidx,
                                        const unsigned short* __restrict__ xb,
                                        int rs, int re, int lane, float& a) {
    int e = rs;
    for (; e + 1 < re; e += 2) {
        int g0 = __builtin_amdgcn_readfirstlane(gidx[e]);
        int g1 = __builtin_amdgcn_readfirstlane(gidx[e + 1]);
        float x0 = bf2f(xb[(g0 << 6) + lane]);
        float x1 = bf2f(xb[(g1 << 6) + lane]);
        a += x0;
        a += x1;
    }
    if (e < re) {
        int g = __builtin_amdgcn_readfirstlane(gidx[e]);
        a += bf2f(xb[(g << 6) + lane]);
    }
}

__global__ __launch_bounds__(256) void k_agg(const int* __restrict__ seg_ptr,
                                             const int* __restrict__ gidx,
                                             const unsigned short* __restrict__ xb,
                                             unsigned short* __restrict__ agg) {
    int wave = threadIdx.x >> 6, lane = threadIdx.x & 63;
    int n = blockIdx.x * 4 + wave;
    if (n >= N_NODES) return;
    const int* sp = seg_ptr + n * 8;
    int p0 = sp[0], p1 = sp[1], p2 = sp[2], p3 = sp[3], p4 = sp[4];
    int p5 = sp[5], p6 = sp[6], p7 = sp[7], p8 = sp[8];
    float a0 = 0.f, a1 = 0.f, a2 = 0.f, a3 = 0.f, a4 = 0.f, a5 = 0.f, a6 = 0.f, a7 = 0.f;
    run_seg(gidx, xb, p0, p1, lane, a0);
    run_seg(gidx, xb, p1, p2, lane, a1);
    run_seg(gidx, xb, p2, p3, lane, a2);
    run_seg(gidx, xb, p3, p4, lane, a3);
    run_seg(gidx, xb, p4, p5, lane, a4);
    run_seg(gidx, xb, p5, p6, lane, a5);
    run_seg(gidx, xb, p6, p7, lane, a6);
    run_seg(gidx, xb, p7, p8, lane, a7);
    unsigned short* o = agg + (size_t)n * 512 + lane;
    o[0 * 64] = f2bf(a0); o[1 * 64] = f2bf(a1); o[2 * 64] = f2bf(a2); o[3 * 64] = f2bf(a3);
    o[4 * 64] = f2bf(a4); o[5 * 64] = f2bf(a5); o[6 * 64] = f2bf(a6); o[7 * 64] = f2bf(a7);
}

// ---------------- MFMA GEMM: h = relu(agg[N,512] @ W[512,64] + b) ----------------
// W staged in LDS pre-permuted into exact B-fragment order:
//   element W[k][o]: c=o>>4 (col-tile), m=o&15 (col), ks=k>>5, q=(k>>3)&3, j=k&7
//   lane = m + 16*q ; pos = ((c*16+ks)*64 + lane)*8 + j  -> stride-1 per-lane ds_read_b128

__global__ __launch_bounds__(256) void k_gemm(const unsigned short* __restrict__ agg,
                                              const float* __restrict__ W,
                                              const float* __restrict__ bias,
                                              unsigned short* __restrict__ out_bf,
                                              float* __restrict__ out_f32) {
    __shared__ unsigned short Wl[32768];   // 64 KB
    int tid = threadIdx.x;
    for (int i = tid; i < 512 * 64; i += 256) {
        int k = i >> 6, o = i & 63;
        int c = o >> 4, m = o & 15;
        int ks = k >> 5, q = (k >> 3) & 3, j = k & 7;
        int pos = (((c * 16 + ks) * 64) + (m + 16 * q)) * 8 + j;
        Wl[pos] = f2bf(W[i]);
    }
    __syncthreads();
    int wave = tid >> 6, lane = tid & 63;
    int tile = blockIdx.x * 4 + wave;
    if (tile >= N_NODES / 16) return;      // 6250 tiles, 16 nodes each (exact)
    int m = lane & 15, q = lane >> 4;
    const unsigned short* arow = agg + ((size_t)(tile * 16 + m)) * 512 + q * 8;
    floatx4 acc[4];
    for (int c = 0; c < 4; ++c) acc[c] = (floatx4){0.f, 0.f, 0.f, 0.f};
    const short8* wl8 = (const short8*)Wl;
#pragma unroll
    for (int ks = 0; ks < 16; ++ks) {
        short8 a = *(const short8*)(arow + ks * 32);
#pragma unroll
        for (int c = 0; c < 4; ++c) {
            short8 b = wl8[(c * 16 + ks) * 64 + lane];
            acc[c] = __builtin_amdgcn_mfma_f32_16x16x32_bf16(a, b, acc[c], 0, 0, 0);
        }
    }
    int node0 = tile * 16;
#pragma unroll
    for (int c = 0; c < 4; ++c) {
        float bb = bias[c * 16 + m];
#pragma unroll
        for (int i = 0; i < 4; ++i) {
            float v = acc[c][i] + bb;
            v = v > 0.f ? v : 0.f;
            int node = node0 + q * 4 + i;                 // C/D: row = quad*4 + reg
            size_t idx = (size_t)node * 64 + c * 16 + m;  //      col = lane&15
            if (out_f32) out_f32[idx] = v;
            if (out_bf) out_bf[idx] = f2bf(v);
        }
    }
}

// ---------------- SSL: out = h2[N,64] @ Wssl[64,64] + bssl ----------------

__global__ __launch_bounds__(256) void k_ssl(const float* __restrict__ h2,
                                             const float* __restrict__ Wssl,
                                             const float* __restrict__ bssl,
                                             float* __restrict__ out) {
    __shared__ float Wl[4096];
    __shared__ float bl[64];
    int tid = threadIdx.x;
    for (int i = tid; i < 4096; i += 256) Wl[i] = Wssl[i];
    if (tid < 64) bl[tid] = bssl[tid];
    __syncthreads();
    int wave = tid >> 6, lane = tid & 63;
    int n = blockIdx.x * 4 + wave;
    if (n >= N_NODES) return;
    float hv = h2[(size_t)n * 64 + lane];
    float acc = bl[lane];
#pragma unroll
    for (int f = 0; f < 64; ++f) acc += __shfl(hv, f, 64) * Wl[f * 64 + lane];
    out[(size_t)n * 64 + lane] = acc;
}

// ---------------- launch ----------------

extern "C" void kernel_launch(void* const* d_in, const int* in_sizes, int n_in,
                              void* d_out, int out_size, void* d_ws, size_t ws_size,
                              hipStream_t stream) {
    const float* x    = (const float*)d_in[0];
    const int*   ei   = (const int*)d_in[1];   // [2,E]: row0 src, row1 dst
    const int*   ti   = (const int*)d_in[2];
    const float* W1   = (const float*)d_in[3];
    const float* b1   = (const float*)d_in[4];
    const float* W2   = (const float*)d_in[5];
    const float* b2   = (const float*)d_in[6];
    const float* Wssl = (const float*)d_in[7];
    const float* bssl = (const float*)d_in[8];
    float* out = (float*)d_out;

    char* w = (char*)d_ws;
    auto alloc = [&](size_t bytes) -> char* {
        char* p = w;
        w += (bytes + 255) & ~(size_t)255;
        return p;
    };
    int* deg      = (int*)alloc((size_t)N_SEGS * 4);
    int* seg_ptr  = (int*)alloc((size_t)(N_SEGS + 1) * 4);
    int* cursor   = (int*)alloc((size_t)N_SEGS * 4);
    int* part     = (int*)alloc((size_t)N_SEGS * 4);
    int* bsum     = (int*)alloc(1024 * 4);
    int* bscan    = (int*)alloc(1024 * 4);
    int* gidx     = (int*)alloc((size_t)N_EDGES * 4);
    unsigned short* xb  = (unsigned short*)alloc((size_t)N_NODES * 64 * 2);
    unsigned short* h1b = (unsigned short*)alloc((size_t)N_NODES * 64 * 2);
    unsigned short* agg = (unsigned short*)alloc((size_t)N_NODES * 512 * 2);

    int nb = (N_SEGS + 1023) / 1024;   // 782

    hipMemsetAsync(deg, 0, (size_t)N_SEGS * 4, stream);
    k_hist<<<(N_EDGES + 255) / 256, 256, 0, stream>>>(ei, ti, deg);
    k_scan_a<<<nb, 1024, 0, stream>>>(deg, part, bsum);
    k_scan_b<<<1, 1024, 0, stream>>>(bsum, bscan, nb);
    k_scan_c<<<nb, 1024, 0, stream>>>(part, bscan, seg_ptr, cursor);
    k_scatter<<<(N_EDGES + 255) / 256, 256, 0, stream>>>(ei, ti, cursor, gidx);
    k_cvt<<<(N_NODES * 64 + 255) / 256, 256, 0, stream>>>(x, xb);

    // conv1: agg(x) -> GEMM W1 -> h1 (bf16 only; relu(relu(.)) == relu(.))
    k_agg<<<(N_NODES + 3) / 4, 256, 0, stream>>>(seg_ptr, gidx, xb, agg);
    k_gemm<<<(N_NODES / 16 + 3) / 4, 256, 0, stream>>>(agg, W1, b1, h1b, nullptr);

    // conv2: agg(h1) -> GEMM W2 -> h2 (fp32, straight to d_out)
    k_agg<<<(N_NODES + 3) / 4, 256, 0, stream>>>(seg_ptr, gidx, h1b, agg);
    k_gemm<<<(N_NODES / 16 + 3) / 4, 256, 0, stream>>>(agg, W2, b2, nullptr, out);

    // ssl: h2 @ Wssl + bssl
    k_ssl<<<(N_NODES + 3) / 4, 256, 0, stream>>>(out, Wssl, bssl, out + (size_t)N_NODES * 64);
}

// Round 3
// 765.792 us; speedup vs baseline: 1.3416x; 1.3416x over previous
//
#include <hip/hip_runtime.h>
#include <hip/hip_bf16.h>

#define N_NODES 100000
#define N_EDGES 3200000
#define T_BUCKETS 8
#define F_DIM 64
#define N_SEGS (N_NODES * T_BUCKETS)   // 800000
#define NB 391                         // ceil(100000/256) buckets of 256 nodes
#define NBP 400                        // padded
#define LSEG 2048                      // 256 nodes * 8 t-buckets per bucket

typedef __attribute__((ext_vector_type(8))) short short8;
typedef __attribute__((ext_vector_type(4))) float floatx4;

__device__ __forceinline__ float bf2f(unsigned short u) {
    unsigned int x = ((unsigned int)u) << 16;
    return __builtin_bit_cast(float, x);
}
__device__ __forceinline__ unsigned short f2bf(float f) {
    unsigned int u = __builtin_bit_cast(unsigned int, f);
    unsigned int r = (u + 0x7FFFu + ((u >> 16) & 1u)) >> 16;
    return (unsigned short)r;
}

// ============ two-level bucketed counting sort by segment (dst*8+t) ============
// word packing: (src << 11) | local_seg, src<2^17, local_seg<2^11  -> 28 bits

// ---- pass 0: global bucket histogram (per-block LDS hist, 1 atomic/bucket/block)
__global__ __launch_bounds__(1024) void k_bhist(const int* __restrict__ ei,
                                                int* __restrict__ bcnt) {
    __shared__ int h[NBP];
    int tid = threadIdx.x;
    if (tid < NBP) h[tid] = 0;
    __syncthreads();
    int base = blockIdx.x * 8192;
#pragma unroll
    for (int i = 0; i < 8; ++i) {
        int e = base + i * 1024 + tid;
        if (e < N_EDGES) atomicAdd(&h[ei[N_EDGES + e] >> 8], 1);
    }
    __syncthreads();
    if (tid < NB && h[tid]) atomicAdd(&bcnt[tid], h[tid]);
}

// ---- pass 1: scan bucket counts -> bucket_base[NB+1]; init cursor
__global__ __launch_bounds__(512) void k_bscan(const int* __restrict__ bcnt,
                                               int* __restrict__ bbase,
                                               int* __restrict__ cursor) {
    __shared__ int s[512];
    int tid = threadIdx.x;
    int v = (tid < NB) ? bcnt[tid] : 0;
    s[tid] = v;
    __syncthreads();
    for (int off = 1; off < 512; off <<= 1) {
        int t = (tid >= off) ? s[tid - off] : 0;
        __syncthreads();
        s[tid] += t;
        __syncthreads();
    }
    if (tid <= NB) {
        int excl = (tid < NB) ? (s[tid] - v) : s[NB - 1];
        bbase[tid] = excl;
        if (tid < NB) cursor[tid] = excl;
    }
}

// ---- pass 2: scatter packed words into bucket-contiguous regions
__global__ __launch_bounds__(1024) void k_bscatter(const int* __restrict__ ei,
                                                   const int* __restrict__ ti,
                                                   int* __restrict__ cursor,
                                                   unsigned int* __restrict__ words) {
    __shared__ int h[NBP];
    __shared__ int bb[NBP];
    __shared__ int lc[NBP];
    int tid = threadIdx.x;
    if (tid < NBP) { h[tid] = 0; lc[tid] = 0; }
    __syncthreads();
    int base = blockIdx.x * 8192;
#pragma unroll
    for (int i = 0; i < 8; ++i) {
        int e = base + i * 1024 + tid;
        if (e < N_EDGES) atomicAdd(&h[ei[N_EDGES + e] >> 8], 1);
    }
    __syncthreads();
    if (tid < NB) {
        int c = h[tid];
        bb[tid] = c ? atomicAdd(&cursor[tid], c) : 0;
    }
    __syncthreads();
#pragma unroll
    for (int i = 0; i < 8; ++i) {
        int e = base + i * 1024 + tid;
        if (e < N_EDGES) {
            int dst = ei[N_EDGES + e];
            int b = dst >> 8;
            int ls = ((dst & 255) << 3) | ti[e];
            int pos = bb[b] + atomicAdd(&lc[b], 1);
            words[pos] = ((unsigned int)ei[e] << 11) | (unsigned int)ls;
        }
    }
}

// ---- pass 3: per-bucket local sort; emits seg_ptr (coalesced) + gidx (L2-local)
__global__ __launch_bounds__(1024) void k_lsort(const int* __restrict__ bbase,
                                                const unsigned int* __restrict__ words,
                                                int* __restrict__ seg_ptr,
                                                int* __restrict__ gidx) {
    __shared__ int h[LSEG];       // local-seg histogram, then global cursor
    __shared__ int ps[1024];      // pair-sum scan buffer
    int tid = threadIdx.x;
    int b = blockIdx.x;
    int rb = bbase[b], re = bbase[b + 1];
    h[tid] = 0; h[tid + 1024] = 0;
    __syncthreads();
    for (int e = rb + tid; e < re; e += 1024)
        atomicAdd(&h[words[e] & 2047u], 1);
    __syncthreads();
    int h0 = h[2 * tid], h1 = h[2 * tid + 1];
    ps[tid] = h0 + h1;
    __syncthreads();
    for (int off = 1; off < 1024; off <<= 1) {
        int t = (tid >= off) ? ps[tid - off] : 0;
        __syncthreads();
        ps[tid] += t;
        __syncthreads();
    }
    int pair_excl = ps[tid] - (h0 + h1);
    __syncthreads();
    // h becomes global cursor; also write seg_ptr
    int g0 = rb + pair_excl, g1 = g0 + h0;
    h[2 * tid] = g0; h[2 * tid + 1] = g1;
    long long gs = (long long)b * LSEG + 2 * tid;
    if (gs < N_SEGS) seg_ptr[gs] = g0;
    if (gs + 1 <= N_SEGS) seg_ptr[gs + 1] = g1;   // index N_SEGS gets N_EDGES-equal value
    __syncthreads();
    for (int e = rb + tid; e < re; e += 1024) {
        unsigned int w = words[e];
        int pos = atomicAdd(&h[w & 2047u], 1);
        gidx[pos] = (int)(w >> 11);
    }
    if (b == NB - 1 && tid == 0) seg_ptr[N_SEGS] = N_EDGES;
}

// ---------------- fp32 -> bf16 table conversion ----------------

__global__ void k_cvt(const float* __restrict__ x, unsigned short* __restrict__ xb) {
    int i = blockIdx.x * 256 + threadIdx.x;
    if (i < N_NODES * F_DIM) xb[i] = f2bf(x[i]);
}

// ---------------- pull aggregation: agg[n][t*64+f] ----------------

__device__ __forceinline__ void run_seg(const int* __restrict__ gidx,
                                        const unsigned short* __restrict__ xb,
                                        int rs, int re, int lane, float& a) {
    int e = rs;
    for (; e + 3 < re; e += 4) {
        int g0 = __builtin_amdgcn_readfirstlane(gidx[e]);
        int g1 = __builtin_amdgcn_readfirstlane(gidx[e + 1]);
        int g2 = __builtin_amdgcn_readfirstlane(gidx[e + 2]);
        int g3 = __builtin_amdgcn_readfirstlane(gidx[e + 3]);
        float x0 = bf2f(xb[(g0 << 6) + lane]);
        float x1 = bf2f(xb[(g1 << 6) + lane]);
        float x2 = bf2f(xb[(g2 << 6) + lane]);
        float x3 = bf2f(xb[(g3 << 6) + lane]);
        a += x0; a += x1; a += x2; a += x3;
    }
    for (; e < re; ++e) {
        int g = __builtin_amdgcn_readfirstlane(gidx[e]);
        a += bf2f(xb[(g << 6) + lane]);
    }
}

__global__ __launch_bounds__(256) void k_agg(const int* __restrict__ seg_ptr,
                                             const int* __restrict__ gidx,
                                             const unsigned short* __restrict__ xb,
                                             unsigned short* __restrict__ agg) {
    int wave = threadIdx.x >> 6, lane = threadIdx.x & 63;
    int n = blockIdx.x * 4 + wave;
    if (n >= N_NODES) return;
    const int* sp = seg_ptr + n * 8;
    int p0 = sp[0], p1 = sp[1], p2 = sp[2], p3 = sp[3], p4 = sp[4];
    int p5 = sp[5], p6 = sp[6], p7 = sp[7], p8 = sp[8];
    float a0 = 0.f, a1 = 0.f, a2 = 0.f, a3 = 0.f, a4 = 0.f, a5 = 0.f, a6 = 0.f, a7 = 0.f;
    run_seg(gidx, xb, p0, p1, lane, a0);
    run_seg(gidx, xb, p1, p2, lane, a1);
    run_seg(gidx, xb, p2, p3, lane, a2);
    run_seg(gidx, xb, p3, p4, lane, a3);
    run_seg(gidx, xb, p4, p5, lane, a4);
    run_seg(gidx, xb, p5, p6, lane, a5);
    run_seg(gidx, xb, p6, p7, lane, a6);
    run_seg(gidx, xb, p7, p8, lane, a7);
    unsigned short* o = agg + (size_t)n * 512 + lane;
    o[0 * 64] = f2bf(a0); o[1 * 64] = f2bf(a1); o[2 * 64] = f2bf(a2); o[3 * 64] = f2bf(a3);
    o[4 * 64] = f2bf(a4); o[5 * 64] = f2bf(a5); o[6 * 64] = f2bf(a6); o[7 * 64] = f2bf(a7);
}

// ---------------- MFMA GEMM: h = relu(agg[N,512] @ W[512,64] + b) ----------------

__global__ __launch_bounds__(256) void k_gemm(const unsigned short* __restrict__ agg,
                                              const float* __restrict__ W,
                                              const float* __restrict__ bias,
                                              unsigned short* __restrict__ out_bf,
                                              float* __restrict__ out_f32) {
    __shared__ unsigned short Wl[32768];   // 64 KB, B-fragment order
    int tid = threadIdx.x;
    for (int i = tid; i < 512 * 64; i += 256) {
        int k = i >> 6, o = i & 63;
        int c = o >> 4, m = o & 15;
        int ks = k >> 5, q = (k >> 3) & 3, j = k & 7;
        int pos = (((c * 16 + ks) * 64) + (m + 16 * q)) * 8 + j;
        Wl[pos] = f2bf(W[i]);
    }
    __syncthreads();
    int wave = tid >> 6, lane = tid & 63;
    int tile = blockIdx.x * 4 + wave;
    if (tile >= N_NODES / 16) return;
    int m = lane & 15, q = lane >> 4;
    const unsigned short* arow = agg + ((size_t)(tile * 16 + m)) * 512 + q * 8;
    floatx4 acc[4];
    for (int c = 0; c < 4; ++c) acc[c] = (floatx4){0.f, 0.f, 0.f, 0.f};
    const short8* wl8 = (const short8*)Wl;
#pragma unroll
    for (int ks = 0; ks < 16; ++ks) {
        short8 a = *(const short8*)(arow + ks * 32);
#pragma unroll
        for (int c = 0; c < 4; ++c) {
            short8 b = wl8[(c * 16 + ks) * 64 + lane];
            acc[c] = __builtin_amdgcn_mfma_f32_16x16x32_bf16(a, b, acc[c], 0, 0, 0);
        }
    }
    int node0 = tile * 16;
#pragma unroll
    for (int c = 0; c < 4; ++c) {
        float bb = bias[c * 16 + m];
#pragma unroll
        for (int i = 0; i < 4; ++i) {
            float v = acc[c][i] + bb;
            v = v > 0.f ? v : 0.f;
            int node = node0 + q * 4 + i;
            size_t idx = (size_t)node * 64 + c * 16 + m;
            if (out_f32) out_f32[idx] = v;
            if (out_bf) out_bf[idx] = f2bf(v);
        }
    }
}

// ---------------- SSL: out = h2[N,64] @ Wssl[64,64] + bssl ----------------

__global__ __launch_bounds__(256) void k_ssl(const float* __restrict__ h2,
                                             const float* __restrict__ Wssl,
                                             const float* __restrict__ bssl,
                                             float* __restrict__ out) {
    __shared__ float Wl[4096];
    __shared__ float bl[64];
    int tid = threadIdx.x;
    for (int i = tid; i < 4096; i += 256) Wl[i] = Wssl[i];
    if (tid < 64) bl[tid] = bssl[tid];
    __syncthreads();
    int wave = tid >> 6, lane = tid & 63;
    int n = blockIdx.x * 4 + wave;
    if (n >= N_NODES) return;
    float hv = h2[(size_t)n * 64 + lane];
    float acc = bl[lane];
#pragma unroll
    for (int f = 0; f < 64; ++f) acc += __shfl(hv, f, 64) * Wl[f * 64 + lane];
    out[(size_t)n * 64 + lane] = acc;
}

// ---------------- launch ----------------

extern "C" void kernel_launch(void* const* d_in, const int* in_sizes, int n_in,
                              void* d_out, int out_size, void* d_ws, size_t ws_size,
                              hipStream_t stream) {
    const float* x    = (const float*)d_in[0];
    const int*   ei   = (const int*)d_in[1];   // [2,E]: row0 src, row1 dst
    const int*   ti   = (const int*)d_in[2];
    const float* W1   = (const float*)d_in[3];
    const float* b1   = (const float*)d_in[4];
    const float* W2   = (const float*)d_in[5];
    const float* b2   = (const float*)d_in[6];
    const float* Wssl = (const float*)d_in[7];
    const float* bssl = (const float*)d_in[8];
    float* out = (float*)d_out;

    char* w = (char*)d_ws;
    auto alloc = [&](size_t bytes) -> char* {
        char* p = w;
        w += (bytes + 255) & ~(size_t)255;
        return p;
    };
    int* bcnt     = (int*)alloc((size_t)NBP * 4);
    int* bbase    = (int*)alloc((size_t)(NB + 1) * 4);
    int* cursor   = (int*)alloc((size_t)NBP * 4);
    unsigned int* words = (unsigned int*)alloc((size_t)N_EDGES * 4);
    int* seg_ptr  = (int*)alloc((size_t)(N_SEGS + 1) * 4);
    int* gidx     = (int*)alloc((size_t)N_EDGES * 4);
    unsigned short* xb  = (unsigned short*)alloc((size_t)N_NODES * 64 * 2);
    unsigned short* h1b = (unsigned short*)alloc((size_t)N_NODES * 64 * 2);
    unsigned short* agg = (unsigned short*)alloc((size_t)N_NODES * 512 * 2);

    int nbe = (N_EDGES + 8191) / 8192;   // 391 edge-blocks

    hipMemsetAsync(bcnt, 0, (size_t)NBP * 4, stream);
    k_bhist<<<nbe, 1024, 0, stream>>>(ei, bcnt);
    k_bscan<<<1, 512, 0, stream>>>(bcnt, bbase, cursor);
    k_bscatter<<<nbe, 1024, 0, stream>>>(ei, ti, cursor, words);
    k_lsort<<<NB, 1024, 0, stream>>>(bbase, words, seg_ptr, gidx);
    k_cvt<<<(N_NODES * 64 + 255) / 256, 256, 0, stream>>>(x, xb);

    // conv1: agg(x) -> GEMM W1 -> h1 (bf16; relu(relu(.)) == relu(.))
    k_agg<<<(N_NODES + 3) / 4, 256, 0, stream>>>(seg_ptr, gidx, xb, agg);
    k_gemm<<<(N_NODES / 16 + 3) / 4, 256, 0, stream>>>(agg, W1, b1, h1b, nullptr);

    // conv2: agg(h1) -> GEMM W2 -> h2 (fp32, straight to d_out)
    k_agg<<<(N_NODES + 3) / 4, 256, 0, stream>>>(seg_ptr, gidx, h1b, agg);
    k_gemm<<<(N_NODES / 16 + 3) / 4, 256, 0, stream>>>(agg, W2, b2, nullptr, out);

    // ssl: h2 @ Wssl + bssl
    k_ssl<<<(N_NODES + 3) / 4, 256, 0, stream>>>(out, Wssl, bssl, out + (size_t)N_NODES * 64);
}

// Round 4
// 652.962 us; speedup vs baseline: 1.5734x; 1.1728x over previous
//
#include <hip/hip_runtime.h>
#include <hip/hip_bf16.h>

#define N_NODES 100000
#define N_EDGES 3200000
#define T_BUCKETS 8
#define F_DIM 64
#define N_SEGS (N_NODES * T_BUCKETS)   // 800000
#define NB 391                         // ceil(100000/256) buckets of 256 nodes
#define NBP 400                        // padded
#define LSEG 2048                      // 256 nodes * 8 t-buckets per bucket

typedef __attribute__((ext_vector_type(8))) short short8;
typedef __attribute__((ext_vector_type(4))) float floatx4;

__device__ __forceinline__ float bf2f(unsigned short u) {
    unsigned int x = ((unsigned int)u) << 16;
    return __builtin_bit_cast(float, x);
}
__device__ __forceinline__ unsigned short f2bf(float f) {
    unsigned int u = __builtin_bit_cast(unsigned int, f);
    unsigned int r = (u + 0x7FFFu + ((u >> 16) & 1u)) >> 16;
    return (unsigned short)r;
}

// ============ two-level bucketed counting sort by segment (dst*8+t) ============
// word packing: (src << 11) | local_seg, src<2^17, local_seg<2^11  -> 28 bits

// ---- pass 0: global bucket histogram (per-block LDS hist, 1 atomic/bucket/block)
__global__ __launch_bounds__(1024) void k_bhist(const int* __restrict__ ei,
                                                int* __restrict__ bcnt) {
    __shared__ int h[NBP];
    int tid = threadIdx.x;
    if (tid < NBP) h[tid] = 0;
    __syncthreads();
    int base = blockIdx.x * 8192;
#pragma unroll
    for (int i = 0; i < 8; ++i) {
        int e = base + i * 1024 + tid;
        if (e < N_EDGES) atomicAdd(&h[ei[N_EDGES + e] >> 8], 1);
    }
    __syncthreads();
    if (tid < NB && h[tid]) atomicAdd(&bcnt[tid], h[tid]);
}

// ---- pass 1: scan bucket counts -> bucket_base[NB+1]; init cursor
__global__ __launch_bounds__(512) void k_bscan(const int* __restrict__ bcnt,
                                               int* __restrict__ bbase,
                                               int* __restrict__ cursor) {
    __shared__ int s[512];
    int tid = threadIdx.x;
    int v = (tid < NB) ? bcnt[tid] : 0;
    s[tid] = v;
    __syncthreads();
    for (int off = 1; off < 512; off <<= 1) {
        int t = (tid >= off) ? s[tid - off] : 0;
        __syncthreads();
        s[tid] += t;
        __syncthreads();
    }
    if (tid <= NB) {
        int excl = (tid < NB) ? (s[tid] - v) : s[NB - 1];
        bbase[tid] = excl;
        if (tid < NB) cursor[tid] = excl;
    }
}

// ---- pass 2: scatter packed words into bucket-contiguous regions
__global__ __launch_bounds__(1024) void k_bscatter(const int* __restrict__ ei,
                                                   const int* __restrict__ ti,
                                                   int* __restrict__ cursor,
                                                   unsigned int* __restrict__ words) {
    __shared__ int h[NBP];
    __shared__ int bb[NBP];
    __shared__ int lc[NBP];
    int tid = threadIdx.x;
    if (tid < NBP) { h[tid] = 0; lc[tid] = 0; }
    __syncthreads();
    int base = blockIdx.x * 8192;
#pragma unroll
    for (int i = 0; i < 8; ++i) {
        int e = base + i * 1024 + tid;
        if (e < N_EDGES) atomicAdd(&h[ei[N_EDGES + e] >> 8], 1);
    }
    __syncthreads();
    if (tid < NB) {
        int c = h[tid];
        bb[tid] = c ? atomicAdd(&cursor[tid], c) : 0;
    }
    __syncthreads();
#pragma unroll
    for (int i = 0; i < 8; ++i) {
        int e = base + i * 1024 + tid;
        if (e < N_EDGES) {
            int dst = ei[N_EDGES + e];
            int b = dst >> 8;
            int ls = ((dst & 255) << 3) | ti[e];
            int pos = bb[b] + atomicAdd(&lc[b], 1);
            words[pos] = ((unsigned int)ei[e] << 11) | (unsigned int)ls;
        }
    }
}

// ---- pass 3: per-bucket local sort; emits seg_ptr (coalesced) + gidx (L2-local)
__global__ __launch_bounds__(1024) void k_lsort(const int* __restrict__ bbase,
                                                const unsigned int* __restrict__ words,
                                                int* __restrict__ seg_ptr,
                                                int* __restrict__ gidx) {
    __shared__ int h[LSEG];       // local-seg histogram, then global cursor
    __shared__ int ps[1024];      // pair-sum scan buffer
    int tid = threadIdx.x;
    int b = blockIdx.x;
    int rb = bbase[b], re = bbase[b + 1];
    h[tid] = 0; h[tid + 1024] = 0;
    __syncthreads();
    for (int e = rb + tid; e < re; e += 1024)
        atomicAdd(&h[words[e] & 2047u], 1);
    __syncthreads();
    int h0 = h[2 * tid], h1 = h[2 * tid + 1];
    ps[tid] = h0 + h1;
    __syncthreads();
    for (int off = 1; off < 1024; off <<= 1) {
        int t = (tid >= off) ? ps[tid - off] : 0;
        __syncthreads();
        ps[tid] += t;
        __syncthreads();
    }
    int pair_excl = ps[tid] - (h0 + h1);
    __syncthreads();
    // h becomes global cursor; also write seg_ptr
    int g0 = rb + pair_excl, g1 = g0 + h0;
    h[2 * tid] = g0; h[2 * tid + 1] = g1;
    long long gs = (long long)b * LSEG + 2 * tid;
    if (gs < N_SEGS) seg_ptr[gs] = g0;
    if (gs + 1 <= N_SEGS) seg_ptr[gs + 1] = g1;
    __syncthreads();
    for (int e = rb + tid; e < re; e += 1024) {
        unsigned int w = words[e];
        int pos = atomicAdd(&h[w & 2047u], 1);
        gidx[pos] = (int)(w >> 11);
    }
    if (b == NB - 1 && tid == 0) seg_ptr[N_SEGS] = N_EDGES;
}

// ---------------- fp32 -> bf16 table conversion ----------------

__global__ void k_cvt(const float* __restrict__ x, unsigned short* __restrict__ xb) {
    int i = blockIdx.x * 256 + threadIdx.x;
    if (i < N_NODES * F_DIM) xb[i] = f2bf(x[i]);
}

// ---------------- pull aggregation: agg[n][t*64+f] ----------------
// Interleaved-segment pipeline: at each step k, issue one gather per t-segment
// (8 independent loads into 8 independent accumulators). Invalid slots clamp
// to the segment's last edge (L1-hot dummy line) with a predicated add.
// Segment pointers are readfirstlane'd so gidx index loads become scalar
// (lgkmcnt) and never serialize against the gathers (vmcnt).

__global__ __launch_bounds__(256) void k_agg(const int* __restrict__ seg_ptr,
                                             const int* __restrict__ gidx,
                                             const unsigned short* __restrict__ xb,
                                             unsigned short* __restrict__ agg) {
    int wave = threadIdx.x >> 6, lane = threadIdx.x & 63;
    int n = blockIdx.x * 4 + wave;
    if (n >= N_NODES) return;
    const int* sp = seg_ptr + n * 8;
    int p[9];
#pragma unroll
    for (int t = 0; t < 9; ++t) p[t] = __builtin_amdgcn_readfirstlane(sp[t]);
    int len[8], clamp_i[8];
    int maxlen = 0;
#pragma unroll
    for (int t = 0; t < 8; ++t) {
        len[t] = p[t + 1] - p[t];
        int c = p[t + 1] - 1;
        clamp_i[t] = c > 0 ? c : 0;
        maxlen = len[t] > maxlen ? len[t] : maxlen;
    }
    float a[8] = {0.f, 0.f, 0.f, 0.f, 0.f, 0.f, 0.f, 0.f};
#pragma unroll 2
    for (int k = 0; k < maxlen; ++k) {
        int g[8];
#pragma unroll
        for (int t = 0; t < 8; ++t) {
            int idx = p[t] + k;
            idx = idx < clamp_i[t] ? idx : clamp_i[t];
            g[t] = gidx[idx];
        }
#pragma unroll
        for (int t = 0; t < 8; ++t) {
            float x = bf2f(xb[((unsigned)g[t] << 6) + lane]);
            a[t] += (k < len[t]) ? x : 0.f;
        }
    }
    unsigned short* o = agg + (size_t)n * 512 + lane;
#pragma unroll
    for (int t = 0; t < 8; ++t) o[t * 64] = f2bf(a[t]);
}

// ---------------- MFMA GEMM: h = relu(agg[N,512] @ W[512,64] + b) ----------------

__global__ __launch_bounds__(256) void k_gemm(const unsigned short* __restrict__ agg,
                                              const float* __restrict__ W,
                                              const float* __restrict__ bias,
                                              unsigned short* __restrict__ out_bf,
                                              float* __restrict__ out_f32) {
    __shared__ unsigned short Wl[32768];   // 64 KB, B-fragment order
    int tid = threadIdx.x;
    for (int i = tid; i < 512 * 64; i += 256) {
        int k = i >> 6, o = i & 63;
        int c = o >> 4, m = o & 15;
        int ks = k >> 5, q = (k >> 3) & 3, j = k & 7;
        int pos = (((c * 16 + ks) * 64) + (m + 16 * q)) * 8 + j;
        Wl[pos] = f2bf(W[i]);
    }
    __syncthreads();
    int wave = tid >> 6, lane = tid & 63;
    int tile = blockIdx.x * 4 + wave;
    if (tile >= N_NODES / 16) return;
    int m = lane & 15, q = lane >> 4;
    const unsigned short* arow = agg + ((size_t)(tile * 16 + m)) * 512 + q * 8;
    floatx4 acc[4];
    for (int c = 0; c < 4; ++c) acc[c] = (floatx4){0.f, 0.f, 0.f, 0.f};
    const short8* wl8 = (const short8*)Wl;
#pragma unroll
    for (int ks = 0; ks < 16; ++ks) {
        short8 a = *(const short8*)(arow + ks * 32);
#pragma unroll
        for (int c = 0; c < 4; ++c) {
            short8 b = wl8[(c * 16 + ks) * 64 + lane];
            acc[c] = __builtin_amdgcn_mfma_f32_16x16x32_bf16(a, b, acc[c], 0, 0, 0);
        }
    }
    int node0 = tile * 16;
#pragma unroll
    for (int c = 0; c < 4; ++c) {
        float bb = bias[c * 16 + m];
#pragma unroll
        for (int i = 0; i < 4; ++i) {
            float v = acc[c][i] + bb;
            v = v > 0.f ? v : 0.f;
            int node = node0 + q * 4 + i;
            size_t idx = (size_t)node * 64 + c * 16 + m;
            if (out_f32) out_f32[idx] = v;
            if (out_bf) out_bf[idx] = f2bf(v);
        }
    }
}

// ---------------- SSL: out = h2[N,64] @ Wssl[64,64] + bssl ----------------

__global__ __launch_bounds__(256) void k_ssl(const float* __restrict__ h2,
                                             const float* __restrict__ Wssl,
                                             const float* __restrict__ bssl,
                                             float* __restrict__ out) {
    __shared__ float Wl[4096];
    __shared__ float bl[64];
    int tid = threadIdx.x;
    for (int i = tid; i < 4096; i += 256) Wl[i] = Wssl[i];
    if (tid < 64) bl[tid] = bssl[tid];
    __syncthreads();
    int wave = tid >> 6, lane = tid & 63;
    int n = blockIdx.x * 4 + wave;
    if (n >= N_NODES) return;
    float hv = h2[(size_t)n * 64 + lane];
    float acc = bl[lane];
#pragma unroll
    for (int f = 0; f < 64; ++f) acc += __shfl(hv, f, 64) * Wl[f * 64 + lane];
    out[(size_t)n * 64 + lane] = acc;
}

// ---------------- launch ----------------

extern "C" void kernel_launch(void* const* d_in, const int* in_sizes, int n_in,
                              void* d_out, int out_size, void* d_ws, size_t ws_size,
                              hipStream_t stream) {
    const float* x    = (const float*)d_in[0];
    const int*   ei   = (const int*)d_in[1];   // [2,E]: row0 src, row1 dst
    const int*   ti   = (const int*)d_in[2];
    const float* W1   = (const float*)d_in[3];
    const float* b1   = (const float*)d_in[4];
    const float* W2   = (const float*)d_in[5];
    const float* b2   = (const float*)d_in[6];
    const float* Wssl = (const float*)d_in[7];
    const float* bssl = (const float*)d_in[8];
    float* out = (float*)d_out;

    char* w = (char*)d_ws;
    auto alloc = [&](size_t bytes) -> char* {
        char* p = w;
        w += (bytes + 255) & ~(size_t)255;
        return p;
    };
    int* bcnt     = (int*)alloc((size_t)NBP * 4);
    int* bbase    = (int*)alloc((size_t)(NB + 1) * 4);
    int* cursor   = (int*)alloc((size_t)NBP * 4);
    unsigned int* words = (unsigned int*)alloc((size_t)N_EDGES * 4);
    int* seg_ptr  = (int*)alloc((size_t)(N_SEGS + 1) * 4);
    int* gidx     = (int*)alloc((size_t)N_EDGES * 4);
    unsigned short* xb  = (unsigned short*)alloc((size_t)N_NODES * 64 * 2);
    unsigned short* h1b = (unsigned short*)alloc((size_t)N_NODES * 64 * 2);
    unsigned short* agg = (unsigned short*)alloc((size_t)N_NODES * 512 * 2);

    int nbe = (N_EDGES + 8191) / 8192;   // 391 edge-blocks

    hipMemsetAsync(bcnt, 0, (size_t)NBP * 4, stream);
    k_bhist<<<nbe, 1024, 0, stream>>>(ei, bcnt);
    k_bscan<<<1, 512, 0, stream>>>(bcnt, bbase, cursor);
    k_bscatter<<<nbe, 1024, 0, stream>>>(ei, ti, cursor, words);
    k_lsort<<<NB, 1024, 0, stream>>>(bbase, words, seg_ptr, gidx);
    k_cvt<<<(N_NODES * 64 + 255) / 256, 256, 0, stream>>>(x, xb);

    // conv1: agg(x) -> GEMM W1 -> h1 (bf16; relu(relu(.)) == relu(.))
    k_agg<<<(N_NODES + 3) / 4, 256, 0, stream>>>(seg_ptr, gidx, xb, agg);
    k_gemm<<<(N_NODES / 16 + 3) / 4, 256, 0, stream>>>(agg, W1, b1, h1b, nullptr);

    // conv2: agg(h1) -> GEMM W2 -> h2 (fp32, straight to d_out)
    k_agg<<<(N_NODES + 3) / 4, 256, 0, stream>>>(seg_ptr, gidx, h1b, agg);
    k_gemm<<<(N_NODES / 16 + 3) / 4, 256, 0, stream>>>(agg, W2, b2, nullptr, out);

    // ssl: h2 @ Wssl + bssl
    k_ssl<<<(N_NODES + 3) / 4, 256, 0, stream>>>(out, Wssl, bssl, out + (size_t)N_NODES * 64);
}

// Round 5
// 579.557 us; speedup vs baseline: 1.7727x; 1.1267x over previous
//
#include <hip/hip_runtime.h>
#include <hip/hip_bf16.h>

#define N_NODES 100000
#define N_EDGES 3200000
#define T_BUCKETS 8
#define F_DIM 64
#define NB 391                         // ceil(100000/256) buckets of 256 nodes
#define NBP 400                        // padded
#define CAP 9216                       // fixed bucket capacity: mean 8184 + 11.4 sigma
#define SPB 2049                       // seg_ptr entries per bucket (2048 starts + end)

typedef __attribute__((ext_vector_type(8))) short short8;
typedef __attribute__((ext_vector_type(4))) float floatx4;

__device__ __forceinline__ float bf2f(unsigned short u) {
    unsigned int x = ((unsigned int)u) << 16;
    return __builtin_bit_cast(float, x);
}
__device__ __forceinline__ unsigned short f2bf(float f) {
    unsigned int u = __builtin_bit_cast(unsigned int, f);
    unsigned int r = (u + 0x7FFFu + ((u >> 16) & 1u)) >> 16;
    return (unsigned short)r;
}

// ============ fixed-capacity bucketed sort by segment (dst*8+t) ============
// bucket b = dst>>8 owns region [b*CAP, b*CAP+count_b). word = (src<<11)|local_seg.

__global__ __launch_bounds__(512) void k_init(int* __restrict__ cursor) {
    int tid = threadIdx.x;
    if (tid < NB) cursor[tid] = tid * CAP;
}

// ---- pass 1: scatter packed words into fixed-cap bucket regions
__global__ __launch_bounds__(1024) void k_bscatter(const int* __restrict__ ei,
                                                   const int* __restrict__ ti,
                                                   int* __restrict__ cursor,
                                                   unsigned int* __restrict__ words) {
    __shared__ int h[NBP];
    __shared__ int bb[NBP];
    __shared__ int lc[NBP];
    int tid = threadIdx.x;
    if (tid < NBP) { h[tid] = 0; lc[tid] = 0; }
    __syncthreads();
    int base = blockIdx.x * 8192;
#pragma unroll
    for (int i = 0; i < 8; ++i) {
        int e = base + i * 1024 + tid;
        if (e < N_EDGES) atomicAdd(&h[ei[N_EDGES + e] >> 8], 1);
    }
    __syncthreads();
    if (tid < NB) {
        int c = h[tid];
        bb[tid] = c ? atomicAdd(&cursor[tid], c) : 0;
    }
    __syncthreads();
#pragma unroll
    for (int i = 0; i < 8; ++i) {
        int e = base + i * 1024 + tid;
        if (e < N_EDGES) {
            int dst = ei[N_EDGES + e];
            int b = dst >> 8;
            int ls = ((dst & 255) << 3) | ti[e];
            int pos = bb[b] + atomicAdd(&lc[b], 1);
            words[pos] = ((unsigned int)ei[e] << 11) | (unsigned int)ls;
        }
    }
}

// ---- pass 2: per-bucket local sort -> seg_ptr[NB][2049] + gidx (bucket-local)
__global__ __launch_bounds__(1024) void k_lsort(const int* __restrict__ cursor,
                                                const unsigned int* __restrict__ words,
                                                int* __restrict__ seg_ptr,
                                                int* __restrict__ gidx) {
    __shared__ int h[2048];       // local-seg histogram, then global cursor
    __shared__ int ps[1024];      // pair-sum scan buffer
    int tid = threadIdx.x;
    int b = blockIdx.x;
    int rb = b * CAP, re = cursor[b];
    h[tid] = 0; h[tid + 1024] = 0;
    __syncthreads();
    for (int e = rb + tid; e < re; e += 1024)
        atomicAdd(&h[words[e] & 2047u], 1);
    __syncthreads();
    int h0 = h[2 * tid], h1 = h[2 * tid + 1];
    ps[tid] = h0 + h1;
    __syncthreads();
    for (int off = 1; off < 1024; off <<= 1) {
        int t = (tid >= off) ? ps[tid - off] : 0;
        __syncthreads();
        ps[tid] += t;
        __syncthreads();
    }
    int pair_excl = ps[tid] - (h0 + h1);
    __syncthreads();
    int g0 = rb + pair_excl, g1 = g0 + h0;
    h[2 * tid] = g0; h[2 * tid + 1] = g1;
    int sb = b * SPB + 2 * tid;
    seg_ptr[sb] = g0;
    seg_ptr[sb + 1] = g1;
    if (tid == 1023) seg_ptr[b * SPB + 2048] = rb + ps[1023];   // bucket end
    __syncthreads();
    for (int e = rb + tid; e < re; e += 1024) {
        unsigned int w = words[e];
        int pos = atomicAdd(&h[w & 2047u], 1);
        gidx[pos] = (int)(w >> 11);
    }
}

// ---------------- prep: fp32 x -> bf16 table; W -> bf16 fragment-order ----------------

__global__ void k_cvt(const float* __restrict__ x, unsigned short* __restrict__ xb) {
    int i = blockIdx.x * 256 + threadIdx.x;
    if (i < N_NODES * F_DIM) xb[i] = f2bf(x[i]);
}

// W[512][64] row-major -> fragment order: pos = ((c*16+ks)*64 + m + 16q)*8 + j
__global__ void k_wprep(const float* __restrict__ W1, const float* __restrict__ W2,
                        unsigned short* __restrict__ Wf1, unsigned short* __restrict__ Wf2) {
    int i = blockIdx.x * 256 + threadIdx.x;
    if (i >= 512 * 64) return;
    int k = i >> 6, o = i & 63;
    int c = o >> 4, m = o & 15;
    int ks = k >> 5, q = (k >> 3) & 3, j = k & 7;
    int pos = (((c * 16 + ks) * 64) + (m + 16 * q)) * 8 + j;
    Wf1[pos] = f2bf(W1[i]);
    Wf2[pos] = f2bf(W2[i]);
}

// ---------------- fused conv: gather-agg (regs) -> LDS A-tile -> MFMA -> relu ----------------
// block = 512 threads (8 waves), 32 nodes. LDS = A-tile only (32 KB, fragment order)
// -> 4 blocks/CU, full 32 waves/CU for the latency-bound gather phase.

__global__ __launch_bounds__(512) void k_fused(const int* __restrict__ seg_ptr,
                                               const int* __restrict__ gidx,
                                               const unsigned short* __restrict__ xb,
                                               const unsigned short* __restrict__ Wf,
                                               const float* __restrict__ bias,
                                               unsigned short* __restrict__ out_bf,
                                               float* __restrict__ out_f32) {
    __shared__ unsigned short Atile[16384];   // 32 nodes x 512 k, bf16, A-fragment order
    int tid = threadIdx.x;
    int wave = tid >> 6, lane = tid & 63;
    int node_base = blockIdx.x * 32;

    // per-lane fragment-write constants (agg phase): k = t*64 + lane
    int f5 = lane >> 5, wq = (lane >> 3) & 3, wj = lane & 7;

    for (int i = 0; i < 4; ++i) {                 // 4 nodes per wave
        int nl = wave * 4 + i;                    // 0..31
        int n = node_base + nl;
        int sb = (n >> 8) * SPB + (n & 255) * 8;
        int p[9];
#pragma unroll
        for (int t = 0; t < 9; ++t) p[t] = __builtin_amdgcn_readfirstlane(seg_ptr[sb + t]);
        int len[8], cl[8];
        int maxlen = 0;
#pragma unroll
        for (int t = 0; t < 8; ++t) {
            len[t] = p[t + 1] - p[t];
            int c = p[t + 1] - 1;
            cl[t] = c > 0 ? c : 0;
            maxlen = len[t] > maxlen ? len[t] : maxlen;
        }
        float a[8] = {0.f, 0.f, 0.f, 0.f, 0.f, 0.f, 0.f, 0.f};
#pragma unroll 2
        for (int k = 0; k < maxlen; ++k) {
            int g[8];
#pragma unroll
            for (int t = 0; t < 8; ++t) {
                int idx = p[t] + k;
                idx = idx < cl[t] ? idx : cl[t];
                g[t] = gidx[idx] & 0x1FFFF;       // mask pad garbage -> safe in-ws read
            }
#pragma unroll
            for (int t = 0; t < 8; ++t) {
                float x = bf2f(xb[((unsigned)g[t] << 6) + lane]);
                a[t] += (k < len[t]) ? x : 0.f;
            }
        }
        // write node's 512 features into A-fragment order:
        // off(t) = nt*8192 + ((t*2+f5)*64 + m + 16*wq)*8 + wj  (shorts)
        int nt = nl >> 4, m = nl & 15;
        int off0 = nt * 8192 + ((f5 * 64) + m + 16 * wq) * 8 + wj;
#pragma unroll
        for (int t = 0; t < 8; ++t) Atile[off0 + t * 1024] = f2bf(a[t]);
    }
    __syncthreads();

    // GEMM phase: wave -> (node-tile nt = wave>>2, col-tile c = wave&3), 16 MFMA
    int nt = wave >> 2, c = wave & 3;
    int m = lane & 15, q = lane >> 4;
    floatx4 acc = (floatx4){0.f, 0.f, 0.f, 0.f};
    const short8* wf8 = (const short8*)Wf;
#pragma unroll
    for (int ks = 0; ks < 16; ++ks) {
        short8 a = *(const short8*)&Atile[nt * 8192 + (ks * 64 + lane) * 8];
        short8 b = wf8[(c * 16 + ks) * 64 + lane];
        acc = __builtin_amdgcn_mfma_f32_16x16x32_bf16(a, b, acc, 0, 0, 0);
    }
    float bb = bias[c * 16 + m];
    int node0 = node_base + nt * 16;
#pragma unroll
    for (int i = 0; i < 4; ++i) {
        float v = acc[i] + bb;
        v = v > 0.f ? v : 0.f;
        int node = node0 + q * 4 + i;                 // C/D: row = quad*4 + reg
        size_t idx = (size_t)node * 64 + c * 16 + m;  //      col = lane&15
        if (out_f32) out_f32[idx] = v;
        if (out_bf) out_bf[idx] = f2bf(v);
    }
}

// ---------------- SSL: out = h2[N,64] @ Wssl[64,64] + bssl ----------------

__global__ __launch_bounds__(256) void k_ssl(const float* __restrict__ h2,
                                             const float* __restrict__ Wssl,
                                             const float* __restrict__ bssl,
                                             float* __restrict__ out) {
    __shared__ float Wl[4096];
    __shared__ float bl[64];
    int tid = threadIdx.x;
    for (int i = tid; i < 4096; i += 256) Wl[i] = Wssl[i];
    if (tid < 64) bl[tid] = bssl[tid];
    __syncthreads();
    int wave = tid >> 6, lane = tid & 63;
    int n = blockIdx.x * 4 + wave;
    if (n >= N_NODES) return;
    float hv = h2[(size_t)n * 64 + lane];
    float acc = bl[lane];
#pragma unroll
    for (int f = 0; f < 64; ++f) acc += __shfl(hv, f, 64) * Wl[f * 64 + lane];
    out[(size_t)n * 64 + lane] = acc;
}

// ---------------- launch ----------------

extern "C" void kernel_launch(void* const* d_in, const int* in_sizes, int n_in,
                              void* d_out, int out_size, void* d_ws, size_t ws_size,
                              hipStream_t stream) {
    const float* x    = (const float*)d_in[0];
    const int*   ei   = (const int*)d_in[1];   // [2,E]: row0 src, row1 dst
    const int*   ti   = (const int*)d_in[2];
    const float* W1   = (const float*)d_in[3];
    const float* b1   = (const float*)d_in[4];
    const float* W2   = (const float*)d_in[5];
    const float* b2   = (const float*)d_in[6];
    const float* Wssl = (const float*)d_in[7];
    const float* bssl = (const float*)d_in[8];
    float* out = (float*)d_out;

    char* w = (char*)d_ws;
    auto alloc = [&](size_t bytes) -> char* {
        char* p = w;
        w += (bytes + 255) & ~(size_t)255;
        return p;
    };
    int* cursor   = (int*)alloc((size_t)NBP * 4);
    unsigned int* words = (unsigned int*)alloc((size_t)NB * CAP * 4);
    int* seg_ptr  = (int*)alloc((size_t)NB * SPB * 4);
    int* gidx     = (int*)alloc((size_t)NB * CAP * 4);
    unsigned short* xb  = (unsigned short*)alloc((size_t)N_NODES * 64 * 2);
    unsigned short* h1b = (unsigned short*)alloc((size_t)N_NODES * 64 * 2);
    unsigned short* Wf1 = (unsigned short*)alloc((size_t)512 * 64 * 2);
    unsigned short* Wf2 = (unsigned short*)alloc((size_t)512 * 64 * 2);

    int nbe = (N_EDGES + 8191) / 8192;   // 391 edge-blocks

    k_init<<<1, 512, 0, stream>>>(cursor);
    k_bscatter<<<nbe, 1024, 0, stream>>>(ei, ti, cursor, words);
    k_lsort<<<NB, 1024, 0, stream>>>(cursor, words, seg_ptr, gidx);
    k_cvt<<<(N_NODES * 64 + 255) / 256, 256, 0, stream>>>(x, xb);
    k_wprep<<<(512 * 64 + 255) / 256, 256, 0, stream>>>(W1, W2, Wf1, Wf2);

    // conv1 fused: agg(xb) + GEMM W1 + relu -> h1b (bf16; relu(relu(.)) == relu(.))
    k_fused<<<N_NODES / 32, 512, 0, stream>>>(seg_ptr, gidx, xb, Wf1, b1, h1b, nullptr);
    // conv2 fused: agg(h1b) + GEMM W2 + relu -> h2 (fp32, straight to d_out)
    k_fused<<<N_NODES / 32, 512, 0, stream>>>(seg_ptr, gidx, h1b, Wf2, b2, nullptr, out);

    // ssl: h2 @ Wssl + bssl
    k_ssl<<<(N_NODES + 3) / 4, 256, 0, stream>>>(out, Wssl, bssl, out + (size_t)N_NODES * 64);
}